// Round 11
// baseline (151.573 us; speedup 1.0000x reference)
//
#include <hip/hip_runtime.h>
#include <hip/hip_bf16.h>

// SelfAttention N=8192, D_IN=512, D_K=64 (fp32 io).
// R10 = R9 with the two unverified micro-opts REVERTED to R8-proven forms
// (failure analysis: finite absmax 124 = key-pair scramble signature, i.e.
// the v_perm-based truncpk byte order; reverted to plain C bit-ops. xor32
// asm swap also reverted to __shfl_xor — not worth the risk).
// KEPT from R9 (exact identities / pure reorders):
//  - exp2-domain scores: Q pre-scaled by log2(e)/8; exp = bare v_exp_f32;
//    defer-max THR=11.0 (e^8-equivalent); merge uses exp2f
//  - per-tile order: QKT(u0,u1) -> sm0 -> PV0 -> sm1 -> PV1 (pipe overlap)
//  - V fragment loads hoisted before softmax
//  - 8 key-splits (grid 512): halves partial traffic
// Structure (proven R8): block-shared dbuf LDS K/V staging via global_load_lds,
// per-wave LDS P-transpose, MFMA-ones rowsum, bf16 partial numerators.

#define N_TOK 8192
#define D_INN 512
#define DK    64
#define QSCALE 0.18033688011112042f  /* log2(e)/8 */

typedef __attribute__((ext_vector_type(8))) short bf16x8;
typedef __attribute__((ext_vector_type(4))) float f32x4;

#define GLOAD_LDS16(gsrc, ldst) \
  __builtin_amdgcn_global_load_lds( \
      (const __attribute__((address_space(1))) unsigned int*)(gsrc), \
      (__attribute__((address_space(3))) unsigned int*)(ldst), 16, 0, 0)

static __device__ __forceinline__ unsigned f2bf_u(float f) {
  union { float f; unsigned u; } v; v.f = f;
  return (v.u + 0x7FFFu + ((v.u >> 16) & 1u)) >> 16;
}
static __device__ __forceinline__ unsigned short f2bf(float f) { return (unsigned short)f2bf_u(f); }
static __device__ __forceinline__ float bf2f(unsigned short h) {
  union { unsigned u; float f; } v; v.u = ((unsigned)h) << 16; return v.f;
}
// R8-proven: lo16 <- hi16(a), hi16 <- hi16(b) (truncation toward zero)
static __device__ __forceinline__ unsigned truncpk(float a, float b) {
  union { float f; unsigned u; } x, y; x.f = a; y.f = b;
  return (x.u >> 16) | (y.u & 0xFFFF0000u);
}
static __device__ __forceinline__ void split2(float a, float b, unsigned& hi, unsigned& lo) {
  unsigned ha = f2bf_u(a), hb = f2bf_u(b);
  float ra = a - bf2f((unsigned short)ha);
  float rb = b - bf2f((unsigned short)hb);
  hi = ha | (hb << 16);
  lo = f2bf_u(ra) | (f2bf_u(rb) << 16);
}
static __device__ __forceinline__ void split8(const float* p, bf16x8& hi, bf16x8& lo) {
  float4 a = *(const float4*)p;
  float4 b = *(const float4*)(p + 4);
  union { unsigned u[4]; bf16x8 v; } H, L;
  split2(a.x, a.y, H.u[0], L.u[0]);
  split2(a.z, a.w, H.u[1], L.u[1]);
  split2(b.x, b.y, H.u[2], L.u[2]);
  split2(b.z, b.w, H.u[3], L.u[3]);
  hi = H.v; lo = L.v;
}
static __device__ __forceinline__ bf16x8 round8(const float* p) {
  float4 a = *(const float4*)p;
  float4 b = *(const float4*)(p + 4);
  union { unsigned u[4]; bf16x8 v; } H;
  H.u[0] = f2bf_u(a.x) | (f2bf_u(a.y) << 16);
  H.u[1] = f2bf_u(a.z) | (f2bf_u(a.w) << 16);
  H.u[2] = f2bf_u(b.x) | (f2bf_u(b.y) << 16);
  H.u[3] = f2bf_u(b.z) | (f2bf_u(b.w) << 16);
  return H.v;
}

// ---------------- QKV projection (inline X and W split) ----------------
__global__ __launch_bounds__(256, 2) void qkv3(
    const float* __restrict__ X,
    const float* __restrict__ Wq, const float* __restrict__ Wk, const float* __restrict__ Wv,
    unsigned short* __restrict__ qhp, unsigned short* __restrict__ qlp,
    unsigned short* __restrict__ kph, unsigned short* __restrict__ kpl,
    unsigned short* __restrict__ vp) {
  const int tid = threadIdx.x, w = tid >> 6, l = tid & 63;
  const int l15 = l & 15, g = l >> 4;
  const int t0 = blockIdx.x * 16;
  const int dq = w * 16;

  f32x4 aq = {0.f, 0.f, 0.f, 0.f}, ak = aq, av = aq;

  for (int kc = 0; kc < D_INN; kc += 32) {
    bf16x8 ah, al;
    split8(X + (t0 + l15) * D_INN + kc + g * 8, ah, al);

    const int woff = (dq + l15) * D_INN + kc + g * 8;
    bf16x8 bqh, bql, bkh, bkl;
    split8(Wq + woff, bqh, bql);
    split8(Wk + woff, bkh, bkl);
    bf16x8 bvh = round8(Wv + woff);

    aq = __builtin_amdgcn_mfma_f32_16x16x32_bf16(ah, bqh, aq, 0, 0, 0);
    aq = __builtin_amdgcn_mfma_f32_16x16x32_bf16(ah, bql, aq, 0, 0, 0);
    aq = __builtin_amdgcn_mfma_f32_16x16x32_bf16(al, bqh, aq, 0, 0, 0);
    ak = __builtin_amdgcn_mfma_f32_16x16x32_bf16(ah, bkh, ak, 0, 0, 0);
    ak = __builtin_amdgcn_mfma_f32_16x16x32_bf16(ah, bkl, ak, 0, 0, 0);
    ak = __builtin_amdgcn_mfma_f32_16x16x32_bf16(al, bkh, ak, 0, 0, 0);
    av = __builtin_amdgcn_mfma_f32_16x16x32_bf16(ah, bvh, av, 0, 0, 0);
    av = __builtin_amdgcn_mfma_f32_16x16x32_bf16(al, bvh, av, 0, 0, 0);
  }

  // Q: fold log2e/8 (exp2-domain scores), split hi/lo, row-major
#pragma unroll
  for (int r = 0; r < 4; r++) {
    float v = aq[r] * QSCALE;
    int row = t0 + g * 4 + r;
    unsigned short h = f2bf(v);
    qhp[row * DK + dq + l15] = h;
    qlp[row * DK + dq + l15] = f2bf(v - bf2f(h));
  }
#pragma unroll
  for (int r = 0; r < 4; r++) {
    float v = ak[r];
    int t = t0 + g * 4 + r;
    int d = dq + l15;
    int off = (t >> 5) * 2048 + ((t >> 4) & 1) * 1024 + (d >> 5) * 512 +
              ((t & 15) + (((d >> 3) & 3) << 4)) * 8 + (d & 7);
    unsigned short h = f2bf(v);
    kph[off] = h;
    kpl[off] = f2bf(v - bf2f(h));
  }
  {
    int tg = t0 + g * 4;
    int d = dq + l15;
    int off = (tg >> 5) * 2048 + (d >> 4) * 512 +
              (((d & 15) + (((tg >> 3) & 3) << 4))) * 8 + (tg & 7);
    uint2 pk;
    pk.x = f2bf_u(av[0]) | (f2bf_u(av[1]) << 16);
    pk.y = f2bf_u(av[2]) | (f2bf_u(av[3]) << 16);
    *(uint2*)(vp + off) = pk;
  }
}

// ---------------- stage one 64-key tile (24KB) into LDS ----------------
static __device__ __forceinline__ void stage_tile(
    const unsigned short* __restrict__ kph, const unsigned short* __restrict__ kpl,
    const unsigned short* __restrict__ vp, int kti,
    unsigned short* lds, int w, int l) {
  const unsigned short* kb = kph + kti * 2048;
  const unsigned short* lb = kpl + kti * 2048;
  const unsigned short* vb = vp + kti * 2048;
#pragma unroll
  for (int j = 0; j < 6; ++j) {
    int chunk = w * 6 + j;
    const unsigned short* src = (chunk < 8) ? kb : ((chunk < 16) ? lb : vb);
    GLOAD_LDS16(src + (chunk & 7) * 512 + l * 8, lds + chunk * 512);
  }
}

// ---------------- flash attention ----------------
// grid 512 = 64 qblocks x 8 key-splits; 256 thr (4 waves); wave: 32 q x 1024 keys.
__global__ __launch_bounds__(256, 2) void attn6(
    const unsigned short* __restrict__ qhp, const unsigned short* __restrict__ qlp,
    const unsigned short* __restrict__ kph, const unsigned short* __restrict__ kpl,
    const unsigned short* __restrict__ vp,
    unsigned short* __restrict__ pnb, float* __restrict__ pden, float* __restrict__ pM) {
  __shared__ unsigned short kv_lds[2 * 12288];   // 2 x 24KB tile buffers
  __shared__ unsigned short P_lds[4 * 16 * 72];  // per-wave P transpose (reused per u)

  const int tid = threadIdx.x, w = tid >> 6, l = tid & 63;
  const int l15 = l & 15, g = l >> 4;
  const int qblk = blockIdx.x >> 3, ks = blockIdx.x & 7;
  const int wq0 = qblk * 128 + w * 32;

  // Q fragments (B-operand of swapped QK^T)
  bf16x8 qhf[2][2], qlf[2][2];
#pragma unroll
  for (int u = 0; u < 2; u++)
#pragma unroll
    for (int c = 0; c < 2; c++) {
      int row = wq0 + u * 16 + l15;
      qhf[u][c] = *(const bf16x8*)(qhp + row * DK + c * 32 + g * 8);
      qlf[u][c] = *(const bf16x8*)(qlp + row * DK + c * 32 + g * 8);
    }

  const short onec = (short)0x3F80;
  const bf16x8 ones = {onec, onec, onec, onec, onec, onec, onec, onec};

  f32x4 accO[2][4], accL[2];
  float m[2] = {-1e30f, -1e30f};
#pragma unroll
  for (int u = 0; u < 2; u++) {
    accL[u] = f32x4{0.f, 0.f, 0.f, 0.f};
#pragma unroll
    for (int ds = 0; ds < 4; ds++) accO[u][ds] = f32x4{0.f, 0.f, 0.f, 0.f};
  }

  const int kti0 = ks * 32;  // 32-key groups; tile t covers kti0+2t, +2t+1
  stage_tile(kph, kpl, vp, kti0, kv_lds, w, l);
  __syncthreads();

  for (int t = 0; t < 16; ++t) {
    const int cb = (t & 1) ? 12288 : 0;
    const int pb = 12288 - cb;
    const int ktin = (t < 15) ? (kti0 + 2 * t + 2) : (kti0 + 2 * t);
    stage_tile(kph, kpl, vp, ktin, kv_lds + pb, w, l);

    const unsigned short* Kh = kv_lds + cb;
    const unsigned short* Kl = Kh + 4096;
    const unsigned short* Vv = Kh + 8192;

    // S^T = K Q^T (log2-domain scores: col = q = lane&15, row = key)
    f32x4 st[2][4];
#pragma unroll
    for (int s = 0; s < 4; s++) {
      bf16x8 khf[2], klf[2];
#pragma unroll
      for (int c = 0; c < 2; c++) {
        const int off = (s >> 1) * 2048 + (s & 1) * 1024 + c * 512 + l * 8;
        khf[c] = *(const bf16x8*)(Kh + off);
        klf[c] = *(const bf16x8*)(Kl + off);
      }
      __builtin_amdgcn_s_setprio(1);
#pragma unroll
      for (int u = 0; u < 2; u++) {
        f32x4 sa = {0.f, 0.f, 0.f, 0.f};
        sa = __builtin_amdgcn_mfma_f32_16x16x32_bf16(khf[0], qhf[u][0], sa, 0, 0, 0);
        sa = __builtin_amdgcn_mfma_f32_16x16x32_bf16(khf[1], qhf[u][1], sa, 0, 0, 0);
        sa = __builtin_amdgcn_mfma_f32_16x16x32_bf16(khf[0], qlf[u][0], sa, 0, 0, 0);
        sa = __builtin_amdgcn_mfma_f32_16x16x32_bf16(khf[1], qlf[u][1], sa, 0, 0, 0);
        sa = __builtin_amdgcn_mfma_f32_16x16x32_bf16(klf[0], qhf[u][0], sa, 0, 0, 0);
        sa = __builtin_amdgcn_mfma_f32_16x16x32_bf16(klf[1], qhf[u][1], sa, 0, 0, 0);
        st[u][s] = sa;
      }
      __builtin_amdgcn_s_setprio(0);
    }

    // V fragments (independent; latency hidden under softmax)
    bf16x8 vb[4][2];
#pragma unroll
    for (int ds = 0; ds < 4; ds++)
#pragma unroll
      for (int c = 0; c < 2; c++)
        vb[ds][c] = *(const bf16x8*)(Vv + c * 2048 + ds * 512 + l * 8);

    // per-u: softmax -> PV (PV(u0) matrix ops overlap softmax(u1) VALU)
#pragma unroll
    for (int u = 0; u < 2; u++) {
      float t0m = fmaxf(fmaxf(st[u][0][0], st[u][0][1]), fmaxf(st[u][0][2], st[u][0][3]));
      float t1m = fmaxf(fmaxf(st[u][1][0], st[u][1][1]), fmaxf(st[u][1][2], st[u][1][3]));
      float t2m = fmaxf(fmaxf(st[u][2][0], st[u][2][1]), fmaxf(st[u][2][2], st[u][2][3]));
      float t3m = fmaxf(fmaxf(st[u][3][0], st[u][3][1]), fmaxf(st[u][3][2], st[u][3][3]));
      float tm = fmaxf(fmaxf(t0m, t1m), fmaxf(t2m, t3m));
      tm = fmaxf(tm, __shfl_xor(tm, 16, 64));
      tm = fmaxf(tm, __shfl_xor(tm, 32, 64));
      if (__any(tm > m[u] + 11.0f)) {  // defer-max (2^11 bound)
        float mn = fmaxf(m[u], tm);
        float fac = exp2f(m[u] - mn);
        m[u] = mn;
#pragma unroll
        for (int r = 0; r < 4; r++) {
          float fr = __shfl(fac, g * 4 + r, 64);
          accL[u][r] *= fr;
#pragma unroll
          for (int ds = 0; ds < 4; ds++) accO[u][ds][r] *= fr;
        }
      }
      // P = exp2(S - m) -> per-wave LDS transpose -> b128 A-frag
      const int base = (w * 16 + l15) * 72;
#pragma unroll
      for (int s = 0; s < 4; s++) {
        float p0 = exp2f(st[u][s][0] - m[u]);
        float p1 = exp2f(st[u][s][1] - m[u]);
        float p2 = exp2f(st[u][s][2] - m[u]);
        float p3 = exp2f(st[u][s][3] - m[u]);
        *(unsigned*)&P_lds[base + s * 16 + g * 4]     = truncpk(p0, p1);
        *(unsigned*)&P_lds[base + s * 16 + g * 4 + 2] = truncpk(p2, p3);
      }
      bf16x8 pa0 = *(const bf16x8*)&P_lds[base + g * 8];
      bf16x8 pa1 = *(const bf16x8*)&P_lds[base + 32 + g * 8];
      __builtin_amdgcn_s_setprio(1);
      accL[u] = __builtin_amdgcn_mfma_f32_16x16x32_bf16(pa0, ones, accL[u], 0, 0, 0);
      accL[u] = __builtin_amdgcn_mfma_f32_16x16x32_bf16(pa1, ones, accL[u], 0, 0, 0);
#pragma unroll
      for (int ds = 0; ds < 4; ds++) {
        accO[u][ds] = __builtin_amdgcn_mfma_f32_16x16x32_bf16(pa0, vb[ds][0], accO[u][ds], 0, 0, 0);
        accO[u][ds] = __builtin_amdgcn_mfma_f32_16x16x32_bf16(pa1, vb[ds][1], accO[u][ds], 0, 0, 0);
      }
      __builtin_amdgcn_s_setprio(0);
    }

    __syncthreads();  // drains vmcnt (prefetch) + lgkm; swap buffers
  }

  // write per-(qblock, key-split) partials (num bf16, den/M fp32)
#pragma unroll
  for (int u = 0; u < 2; u++) {
#pragma unroll
    for (int ds = 0; ds < 4; ds++)
#pragma unroll
      for (int r = 0; r < 4; r++)
        pnb[(size_t)ks * (N_TOK * DK) + (wq0 + u * 16 + g * 4 + r) * DK + ds * 16 + l15] =
            f2bf(accO[u][ds][r]);
    if (l15 == 0) {
#pragma unroll
      for (int r = 0; r < 4; r++) pden[ks * N_TOK + wq0 + u * 16 + g * 4 + r] = accL[u][r];
    }
    if (g == 0) pM[ks * N_TOK + wq0 + u * 16 + l15] = m[u];
  }
}

// ---------------- merge 8 key-split partials (log2 domain) ----------------
__global__ __launch_bounds__(256) void merge8(
    const unsigned short* __restrict__ pnb, const float* __restrict__ pden,
    const float* __restrict__ pM, float* __restrict__ out) {
  int i = blockIdx.x * 256 + threadIdx.x;
  int q = i >> 6, d = i & 63;
  float M = -1e30f;
#pragma unroll
  for (int s = 0; s < 8; s++) M = fmaxf(M, pM[s * N_TOK + q]);
  float num = 0.f, den = 0.f;
#pragma unroll
  for (int s = 0; s < 8; s++) {
    float e = exp2f(pM[s * N_TOK + q] - M);
    num += bf2f(pnb[(size_t)s * (N_TOK * DK) + q * DK + d]) * e;
    den += pden[s * N_TOK + q] * e;
  }
  out[i] = num / den;
}

// ---------------- host launch ----------------
extern "C" void kernel_launch(void* const* d_in, const int* in_sizes, int n_in,
                              void* d_out, int out_size, void* d_ws, size_t ws_size,
                              hipStream_t stream) {
  (void)in_sizes; (void)n_in; (void)out_size; (void)ws_size;
  const float* X  = (const float*)d_in[0];
  const float* Wq = (const float*)d_in[1];
  const float* Wk = (const float*)d_in[2];
  const float* Wv = (const float*)d_in[3];

  char* base = (char*)d_ws;
  unsigned short* pnb = (unsigned short*)(base);                  // 8 MB [8][8192][64] bf16
  unsigned short* qhp = (unsigned short*)(base + 16777216);       // 1 MB
  unsigned short* qlp = (unsigned short*)(base + 17825792);       // 1 MB
  unsigned short* kph = (unsigned short*)(base + 18874368);       // 1 MB
  unsigned short* kpl = (unsigned short*)(base + 19922944);       // 1 MB
  unsigned short* vp  = (unsigned short*)(base + 20971520);       // 1 MB
  float* pden = (float*)(base + 22020096);                        // 256 KB
  float* pM   = (float*)(base + 22544384);                        // 256 KB

  qkv3<<<N_TOK / 16, 256, 0, stream>>>(X, Wq, Wk, Wv, qhp, qlp, kph, kpl, vp);
  attn6<<<512, 256, 0, stream>>>(qhp, qlp, kph, kpl, vp, pnb, pden, pM);
  merge8<<<(N_TOK * DK) / 256, 256, 0, stream>>>(pnb, pden, pM, (float*)d_out);
}

// Round 12
// 148.178 us; speedup vs baseline: 1.0229x; 1.0229x over previous
//
#include <hip/hip_runtime.h>
#include <hip/hip_bf16.h>

// SelfAttention N=8192, D_IN=512, D_K=64 (fp32 io).
// R11 = revert to the R3/R6-proven attn skeleton (global frag-ordered K/V
// loads, 18KB LDS, SEPARATE per-u P_lds regions -> independent softmax
// chains), keeping only the verified-safe R9/R10 identities:
//  - exp2-domain scores (QSCALE=log2e/8, bare v_exp_f32, defer-max THR=11)
//  - V fragment loads hoisted before softmax
//  - 8 key-splits (grid 512; R3's 49.6 beat 16-split 53.4)
// R10's lessons: P_lds reuse serialized the u0/u1 chains (+5us); 58KB LDS
// staging was neutral but capped occupancy at 2 blocks/CU. Both dropped.

#define N_TOK 8192
#define D_INN 512
#define DK    64
#define QSCALE 0.18033688011112042f  /* log2(e)/8 */

typedef __attribute__((ext_vector_type(8))) short bf16x8;
typedef __attribute__((ext_vector_type(4))) float f32x4;

static __device__ __forceinline__ unsigned f2bf_u(float f) {
  union { float f; unsigned u; } v; v.f = f;
  return (v.u + 0x7FFFu + ((v.u >> 16) & 1u)) >> 16;
}
static __device__ __forceinline__ unsigned short f2bf(float f) { return (unsigned short)f2bf_u(f); }
static __device__ __forceinline__ float bf2f(unsigned short h) {
  union { unsigned u; float f; } v; v.u = ((unsigned)h) << 16; return v.f;
}
static __device__ __forceinline__ unsigned truncpk(float a, float b) {
  union { float f; unsigned u; } x, y; x.f = a; y.f = b;
  return (x.u >> 16) | (y.u & 0xFFFF0000u);
}
static __device__ __forceinline__ void split2(float a, float b, unsigned& hi, unsigned& lo) {
  unsigned ha = f2bf_u(a), hb = f2bf_u(b);
  float ra = a - bf2f((unsigned short)ha);
  float rb = b - bf2f((unsigned short)hb);
  hi = ha | (hb << 16);
  lo = f2bf_u(ra) | (f2bf_u(rb) << 16);
}
static __device__ __forceinline__ void split8(const float* p, bf16x8& hi, bf16x8& lo) {
  float4 a = *(const float4*)p;
  float4 b = *(const float4*)(p + 4);
  union { unsigned u[4]; bf16x8 v; } H, L;
  split2(a.x, a.y, H.u[0], L.u[0]);
  split2(a.z, a.w, H.u[1], L.u[1]);
  split2(b.x, b.y, H.u[2], L.u[2]);
  split2(b.z, b.w, H.u[3], L.u[3]);
  hi = H.v; lo = L.v;
}
static __device__ __forceinline__ bf16x8 round8(const float* p) {
  float4 a = *(const float4*)p;
  float4 b = *(const float4*)(p + 4);
  union { unsigned u[4]; bf16x8 v; } H;
  H.u[0] = f2bf_u(a.x) | (f2bf_u(a.y) << 16);
  H.u[1] = f2bf_u(a.z) | (f2bf_u(a.w) << 16);
  H.u[2] = f2bf_u(b.x) | (f2bf_u(b.y) << 16);
  H.u[3] = f2bf_u(b.z) | (f2bf_u(b.w) << 16);
  return H.v;
}

// ---------------- QKV projection (inline X and W split) ----------------
__global__ __launch_bounds__(256, 2) void qkv3(
    const float* __restrict__ X,
    const float* __restrict__ Wq, const float* __restrict__ Wk, const float* __restrict__ Wv,
    unsigned short* __restrict__ qhp, unsigned short* __restrict__ qlp,
    unsigned short* __restrict__ kph, unsigned short* __restrict__ kpl,
    unsigned short* __restrict__ vp) {
  const int tid = threadIdx.x, w = tid >> 6, l = tid & 63;
  const int l15 = l & 15, g = l >> 4;
  const int t0 = blockIdx.x * 16;
  const int dq = w * 16;

  f32x4 aq = {0.f, 0.f, 0.f, 0.f}, ak = aq, av = aq;

  for (int kc = 0; kc < D_INN; kc += 32) {
    bf16x8 ah, al;
    split8(X + (t0 + l15) * D_INN + kc + g * 8, ah, al);

    const int woff = (dq + l15) * D_INN + kc + g * 8;
    bf16x8 bqh, bql, bkh, bkl;
    split8(Wq + woff, bqh, bql);
    split8(Wk + woff, bkh, bkl);
    bf16x8 bvh = round8(Wv + woff);

    aq = __builtin_amdgcn_mfma_f32_16x16x32_bf16(ah, bqh, aq, 0, 0, 0);
    aq = __builtin_amdgcn_mfma_f32_16x16x32_bf16(ah, bql, aq, 0, 0, 0);
    aq = __builtin_amdgcn_mfma_f32_16x16x32_bf16(al, bqh, aq, 0, 0, 0);
    ak = __builtin_amdgcn_mfma_f32_16x16x32_bf16(ah, bkh, ak, 0, 0, 0);
    ak = __builtin_amdgcn_mfma_f32_16x16x32_bf16(ah, bkl, ak, 0, 0, 0);
    ak = __builtin_amdgcn_mfma_f32_16x16x32_bf16(al, bkh, ak, 0, 0, 0);
    av = __builtin_amdgcn_mfma_f32_16x16x32_bf16(ah, bvh, av, 0, 0, 0);
    av = __builtin_amdgcn_mfma_f32_16x16x32_bf16(al, bvh, av, 0, 0, 0);
  }

  // Q: fold log2e/8 (exp2-domain scores), split hi/lo, row-major
#pragma unroll
  for (int r = 0; r < 4; r++) {
    float v = aq[r] * QSCALE;
    int row = t0 + g * 4 + r;
    unsigned short h = f2bf(v);
    qhp[row * DK + dq + l15] = h;
    qlp[row * DK + dq + l15] = f2bf(v - bf2f(h));
  }
#pragma unroll
  for (int r = 0; r < 4; r++) {
    float v = ak[r];
    int t = t0 + g * 4 + r;
    int d = dq + l15;
    int off = (t >> 5) * 2048 + ((t >> 4) & 1) * 1024 + (d >> 5) * 512 +
              ((t & 15) + (((d >> 3) & 3) << 4)) * 8 + (d & 7);
    unsigned short h = f2bf(v);
    kph[off] = h;
    kpl[off] = f2bf(v - bf2f(h));
  }
  {
    int tg = t0 + g * 4;
    int d = dq + l15;
    int off = (tg >> 5) * 2048 + (d >> 4) * 512 +
              (((d & 15) + (((tg >> 3) & 3) << 4))) * 8 + (tg & 7);
    uint2 pk;
    pk.x = f2bf_u(av[0]) | (f2bf_u(av[1]) << 16);
    pk.y = f2bf_u(av[2]) | (f2bf_u(av[3]) << 16);
    *(uint2*)(vp + off) = pk;
  }
}

// ---------------- flash attention ----------------
// grid 512 = 64 qblocks x 8 key-splits; 256 thr (4 waves); wave: 32 q x 1024 keys.
__global__ __launch_bounds__(256, 2) void attn7(
    const unsigned short* __restrict__ qhp, const unsigned short* __restrict__ qlp,
    const unsigned short* __restrict__ kph, const unsigned short* __restrict__ kpl,
    const unsigned short* __restrict__ vp,
    unsigned short* __restrict__ pnb, float* __restrict__ pden, float* __restrict__ pM) {
  // SEPARATE per-(wave,u) P staging: [4][2][16][72] -> independent sm chains
  __shared__ unsigned short P_lds[4 * 2 * 16 * 72];

  const int tid = threadIdx.x, w = tid >> 6, l = tid & 63;
  const int l15 = l & 15, g = l >> 4;
  const int qblk = blockIdx.x >> 3, ks = blockIdx.x & 7;
  const int wq0 = qblk * 128 + w * 32;

  // Q fragments (B-operand of swapped QK^T)
  bf16x8 qhf[2][2], qlf[2][2];
#pragma unroll
  for (int u = 0; u < 2; u++)
#pragma unroll
    for (int c = 0; c < 2; c++) {
      int row = wq0 + u * 16 + l15;
      qhf[u][c] = *(const bf16x8*)(qhp + row * DK + c * 32 + g * 8);
      qlf[u][c] = *(const bf16x8*)(qlp + row * DK + c * 32 + g * 8);
    }

  const short onec = (short)0x3F80;
  const bf16x8 ones = {onec, onec, onec, onec, onec, onec, onec, onec};

  f32x4 accO[2][4], accL[2];
  float m[2] = {-1e30f, -1e30f};
#pragma unroll
  for (int u = 0; u < 2; u++) {
    accL[u] = f32x4{0.f, 0.f, 0.f, 0.f};
#pragma unroll
    for (int ds = 0; ds < 4; ds++) accO[u][ds] = f32x4{0.f, 0.f, 0.f, 0.f};
  }

  for (int kt = ks * 1024; kt < ks * 1024 + 1024; kt += 64) {
    const int kti = kt >> 5;

    // S^T = K Q^T (log2-domain scores: col = q = lane&15, row = key)
    f32x4 st[2][4];
#pragma unroll
    for (int s = 0; s < 4; s++) {
      bf16x8 khf[2], klf[2];
#pragma unroll
      for (int c = 0; c < 2; c++) {
        const int off = (kti + (s >> 1)) * 2048 + (s & 1) * 1024 + c * 512 + l * 8;
        khf[c] = *(const bf16x8*)(kph + off);
        klf[c] = *(const bf16x8*)(kpl + off);
      }
      __builtin_amdgcn_s_setprio(1);
#pragma unroll
      for (int u = 0; u < 2; u++) {
        f32x4 sa = {0.f, 0.f, 0.f, 0.f};
        sa = __builtin_amdgcn_mfma_f32_16x16x32_bf16(khf[0], qhf[u][0], sa, 0, 0, 0);
        sa = __builtin_amdgcn_mfma_f32_16x16x32_bf16(khf[1], qhf[u][1], sa, 0, 0, 0);
        sa = __builtin_amdgcn_mfma_f32_16x16x32_bf16(khf[0], qlf[u][0], sa, 0, 0, 0);
        sa = __builtin_amdgcn_mfma_f32_16x16x32_bf16(khf[1], qlf[u][1], sa, 0, 0, 0);
        sa = __builtin_amdgcn_mfma_f32_16x16x32_bf16(klf[0], qhf[u][0], sa, 0, 0, 0);
        sa = __builtin_amdgcn_mfma_f32_16x16x32_bf16(klf[1], qhf[u][1], sa, 0, 0, 0);
        st[u][s] = sa;
      }
      __builtin_amdgcn_s_setprio(0);
    }

    // V fragments (global, coalesced; latency hidden under softmax)
    bf16x8 vb[4][2];
#pragma unroll
    for (int ds = 0; ds < 4; ds++)
#pragma unroll
      for (int c = 0; c < 2; c++)
        vb[ds][c] = *(const bf16x8*)(vp + (kti + c) * 2048 + ds * 512 + l * 8);

    // two INDEPENDENT softmax chains (separate P_lds regions)
    bf16x8 pa[2][2];
#pragma unroll
    for (int u = 0; u < 2; u++) {
      float t0m = fmaxf(fmaxf(st[u][0][0], st[u][0][1]), fmaxf(st[u][0][2], st[u][0][3]));
      float t1m = fmaxf(fmaxf(st[u][1][0], st[u][1][1]), fmaxf(st[u][1][2], st[u][1][3]));
      float t2m = fmaxf(fmaxf(st[u][2][0], st[u][2][1]), fmaxf(st[u][2][2], st[u][2][3]));
      float t3m = fmaxf(fmaxf(st[u][3][0], st[u][3][1]), fmaxf(st[u][3][2], st[u][3][3]));
      float tm = fmaxf(fmaxf(t0m, t1m), fmaxf(t2m, t3m));
      tm = fmaxf(tm, __shfl_xor(tm, 16, 64));
      tm = fmaxf(tm, __shfl_xor(tm, 32, 64));
      if (__any(tm > m[u] + 11.0f)) {  // defer-max (2^11 bound)
        float mn = fmaxf(m[u], tm);
        float fac = exp2f(m[u] - mn);
        m[u] = mn;
#pragma unroll
        for (int r = 0; r < 4; r++) {
          float fr = __shfl(fac, g * 4 + r, 64);
          accL[u][r] *= fr;
#pragma unroll
          for (int ds = 0; ds < 4; ds++) accO[u][ds][r] *= fr;
        }
      }
      // P = exp2(S - m) -> per-(wave,u) LDS transpose -> b128 A-frag
      const int base = ((w * 2 + u) * 16 + l15) * 72;
#pragma unroll
      for (int s = 0; s < 4; s++) {
        float p0 = exp2f(st[u][s][0] - m[u]);
        float p1 = exp2f(st[u][s][1] - m[u]);
        float p2 = exp2f(st[u][s][2] - m[u]);
        float p3 = exp2f(st[u][s][3] - m[u]);
        *(unsigned*)&P_lds[base + s * 16 + g * 4]     = truncpk(p0, p1);
        *(unsigned*)&P_lds[base + s * 16 + g * 4 + 2] = truncpk(p2, p3);
      }
#pragma unroll
      for (int c = 0; c < 2; c++)
        pa[u][c] = *(const bf16x8*)&P_lds[base + c * 32 + g * 8];
      accL[u] = __builtin_amdgcn_mfma_f32_16x16x32_bf16(pa[u][0], ones, accL[u], 0, 0, 0);
      accL[u] = __builtin_amdgcn_mfma_f32_16x16x32_bf16(pa[u][1], ones, accL[u], 0, 0, 0);
    }

    // PV
    __builtin_amdgcn_s_setprio(1);
#pragma unroll
    for (int ds = 0; ds < 4; ds++)
#pragma unroll
      for (int u = 0; u < 2; u++) {
        accO[u][ds] = __builtin_amdgcn_mfma_f32_16x16x32_bf16(pa[u][0], vb[ds][0], accO[u][ds], 0, 0, 0);
        accO[u][ds] = __builtin_amdgcn_mfma_f32_16x16x32_bf16(pa[u][1], vb[ds][1], accO[u][ds], 0, 0, 0);
      }
    __builtin_amdgcn_s_setprio(0);
  }

  // write per-(qblock, key-split) partials (num bf16, den/M fp32)
#pragma unroll
  for (int u = 0; u < 2; u++) {
#pragma unroll
    for (int ds = 0; ds < 4; ds++)
#pragma unroll
      for (int r = 0; r < 4; r++)
        pnb[(size_t)ks * (N_TOK * DK) + (wq0 + u * 16 + g * 4 + r) * DK + ds * 16 + l15] =
            f2bf(accO[u][ds][r]);
    if (l15 == 0) {
#pragma unroll
      for (int r = 0; r < 4; r++) pden[ks * N_TOK + wq0 + u * 16 + g * 4 + r] = accL[u][r];
    }
    if (g == 0) pM[ks * N_TOK + wq0 + u * 16 + l15] = m[u];
  }
}

// ---------------- merge 8 key-split partials (log2 domain) ----------------
__global__ __launch_bounds__(256) void merge8(
    const unsigned short* __restrict__ pnb, const float* __restrict__ pden,
    const float* __restrict__ pM, float* __restrict__ out) {
  int i = blockIdx.x * 256 + threadIdx.x;
  int q = i >> 6, d = i & 63;
  float M = -1e30f;
#pragma unroll
  for (int s = 0; s < 8; s++) M = fmaxf(M, pM[s * N_TOK + q]);
  float num = 0.f, den = 0.f;
#pragma unroll
  for (int s = 0; s < 8; s++) {
    float e = exp2f(pM[s * N_TOK + q] - M);
    num += bf2f(pnb[(size_t)s * (N_TOK * DK) + q * DK + d]) * e;
    den += pden[s * N_TOK + q] * e;
  }
  out[i] = num / den;
}

// ---------------- host launch ----------------
extern "C" void kernel_launch(void* const* d_in, const int* in_sizes, int n_in,
                              void* d_out, int out_size, void* d_ws, size_t ws_size,
                              hipStream_t stream) {
  (void)in_sizes; (void)n_in; (void)out_size; (void)ws_size;
  const float* X  = (const float*)d_in[0];
  const float* Wq = (const float*)d_in[1];
  const float* Wk = (const float*)d_in[2];
  const float* Wv = (const float*)d_in[3];

  char* base = (char*)d_ws;
  unsigned short* pnb = (unsigned short*)(base);                  // 8 MB [8][8192][64] bf16
  unsigned short* qhp = (unsigned short*)(base + 16777216);       // 1 MB
  unsigned short* qlp = (unsigned short*)(base + 17825792);       // 1 MB
  unsigned short* kph = (unsigned short*)(base + 18874368);       // 1 MB
  unsigned short* kpl = (unsigned short*)(base + 19922944);       // 1 MB
  unsigned short* vp  = (unsigned short*)(base + 20971520);       // 1 MB
  float* pden = (float*)(base + 22020096);                        // 256 KB
  float* pM   = (float*)(base + 22544384);                        // 256 KB

  qkv3<<<N_TOK / 16, 256, 0, stream>>>(X, Wq, Wk, Wv, qhp, qlp, kph, kpl, vp);
  attn7<<<512, 256, 0, stream>>>(qhp, qlp, kph, kpl, vp, pnb, pden, pM);
  merge8<<<(N_TOK * DK) / 256, 256, 0, stream>>>(pnb, pden, pM, (float*)d_out);
}

// Round 13
// 147.944 us; speedup vs baseline: 1.0245x; 1.0016x over previous
//
#include <hip/hip_runtime.h>
#include <hip/hip_bf16.h>

// SelfAttention N=8192, D_IN=512, D_K=64 (fp32 io).
// R12: occupancy via SMALLER WAVE STATE (R5 showed forcing regs fails; R6/R11
// showed 92 arch + ~40 acc > 128 pins us at 2 waves/SIMD):
//  - attn8: 512 thr = 8 waves, 16 q/wave (u-loop gone) -> ~100 total regs,
//    __launch_bounds__(512,4) caps 128 -> 4 waves/SIMD, 2 blocks/CU, 16 w/CU.
//  - 32-key tiles double-buffer staged in LDS (24KB) + per-wave P_lds (10KB)
//    = 34KB static; K/V shared by 8 waves (L2 ~200MB total).
//  - softmax reverted to R3-proven __expf / e-domain / THR=8 (R11 lesson:
//    exp2f is a slow libm call, VALUBusy 34->44).
// qkv3: QSCALE back to 0.125. merge8 unchanged (e-domain).

#define N_TOK 8192
#define D_INN 512
#define DK    64

typedef __attribute__((ext_vector_type(8))) short bf16x8;
typedef __attribute__((ext_vector_type(4))) float f32x4;

#define GLOAD_LDS16(gsrc, ldst) \
  __builtin_amdgcn_global_load_lds( \
      (const __attribute__((address_space(1))) unsigned int*)(gsrc), \
      (__attribute__((address_space(3))) unsigned int*)(ldst), 16, 0, 0)

static __device__ __forceinline__ unsigned f2bf_u(float f) {
  union { float f; unsigned u; } v; v.f = f;
  return (v.u + 0x7FFFu + ((v.u >> 16) & 1u)) >> 16;
}
static __device__ __forceinline__ unsigned short f2bf(float f) { return (unsigned short)f2bf_u(f); }
static __device__ __forceinline__ float bf2f(unsigned short h) {
  union { unsigned u; float f; } v; v.u = ((unsigned)h) << 16; return v.f;
}
static __device__ __forceinline__ unsigned truncpk(float a, float b) {
  union { float f; unsigned u; } x, y; x.f = a; y.f = b;
  return (x.u >> 16) | (y.u & 0xFFFF0000u);
}
static __device__ __forceinline__ void split2(float a, float b, unsigned& hi, unsigned& lo) {
  unsigned ha = f2bf_u(a), hb = f2bf_u(b);
  float ra = a - bf2f((unsigned short)ha);
  float rb = b - bf2f((unsigned short)hb);
  hi = ha | (hb << 16);
  lo = f2bf_u(ra) | (f2bf_u(rb) << 16);
}
static __device__ __forceinline__ void split8(const float* p, bf16x8& hi, bf16x8& lo) {
  float4 a = *(const float4*)p;
  float4 b = *(const float4*)(p + 4);
  union { unsigned u[4]; bf16x8 v; } H, L;
  split2(a.x, a.y, H.u[0], L.u[0]);
  split2(a.z, a.w, H.u[1], L.u[1]);
  split2(b.x, b.y, H.u[2], L.u[2]);
  split2(b.z, b.w, H.u[3], L.u[3]);
  hi = H.v; lo = L.v;
}
static __device__ __forceinline__ bf16x8 round8(const float* p) {
  float4 a = *(const float4*)p;
  float4 b = *(const float4*)(p + 4);
  union { unsigned u[4]; bf16x8 v; } H;
  H.u[0] = f2bf_u(a.x) | (f2bf_u(a.y) << 16);
  H.u[1] = f2bf_u(a.z) | (f2bf_u(a.w) << 16);
  H.u[2] = f2bf_u(b.x) | (f2bf_u(b.y) << 16);
  H.u[3] = f2bf_u(b.z) | (f2bf_u(b.w) << 16);
  return H.v;
}

// ---------------- QKV projection (inline X and W split) ----------------
__global__ __launch_bounds__(256, 2) void qkv3(
    const float* __restrict__ X,
    const float* __restrict__ Wq, const float* __restrict__ Wk, const float* __restrict__ Wv,
    unsigned short* __restrict__ qhp, unsigned short* __restrict__ qlp,
    unsigned short* __restrict__ kph, unsigned short* __restrict__ kpl,
    unsigned short* __restrict__ vp) {
  const int tid = threadIdx.x, w = tid >> 6, l = tid & 63;
  const int l15 = l & 15, g = l >> 4;
  const int t0 = blockIdx.x * 16;
  const int dq = w * 16;

  f32x4 aq = {0.f, 0.f, 0.f, 0.f}, ak = aq, av = aq;

  for (int kc = 0; kc < D_INN; kc += 32) {
    bf16x8 ah, al;
    split8(X + (t0 + l15) * D_INN + kc + g * 8, ah, al);

    const int woff = (dq + l15) * D_INN + kc + g * 8;
    bf16x8 bqh, bql, bkh, bkl;
    split8(Wq + woff, bqh, bql);
    split8(Wk + woff, bkh, bkl);
    bf16x8 bvh = round8(Wv + woff);

    aq = __builtin_amdgcn_mfma_f32_16x16x32_bf16(ah, bqh, aq, 0, 0, 0);
    aq = __builtin_amdgcn_mfma_f32_16x16x32_bf16(ah, bql, aq, 0, 0, 0);
    aq = __builtin_amdgcn_mfma_f32_16x16x32_bf16(al, bqh, aq, 0, 0, 0);
    ak = __builtin_amdgcn_mfma_f32_16x16x32_bf16(ah, bkh, ak, 0, 0, 0);
    ak = __builtin_amdgcn_mfma_f32_16x16x32_bf16(ah, bkl, ak, 0, 0, 0);
    ak = __builtin_amdgcn_mfma_f32_16x16x32_bf16(al, bkh, ak, 0, 0, 0);
    av = __builtin_amdgcn_mfma_f32_16x16x32_bf16(ah, bvh, av, 0, 0, 0);
    av = __builtin_amdgcn_mfma_f32_16x16x32_bf16(al, bvh, av, 0, 0, 0);
  }

  // Q: fold 1/8 (e-domain), split hi/lo, row-major
#pragma unroll
  for (int r = 0; r < 4; r++) {
    float v = aq[r] * 0.125f;
    int row = t0 + g * 4 + r;
    unsigned short h = f2bf(v);
    qhp[row * DK + dq + l15] = h;
    qlp[row * DK + dq + l15] = f2bf(v - bf2f(h));
  }
#pragma unroll
  for (int r = 0; r < 4; r++) {
    float v = ak[r];
    int t = t0 + g * 4 + r;
    int d = dq + l15;
    int off = (t >> 5) * 2048 + ((t >> 4) & 1) * 1024 + (d >> 5) * 512 +
              ((t & 15) + (((d >> 3) & 3) << 4)) * 8 + (d & 7);
    unsigned short h = f2bf(v);
    kph[off] = h;
    kpl[off] = f2bf(v - bf2f(h));
  }
  {
    int tg = t0 + g * 4;
    int d = dq + l15;
    int off = (tg >> 5) * 2048 + (d >> 4) * 512 +
              (((d & 15) + (((tg >> 3) & 3) << 4))) * 8 + (tg & 7);
    uint2 pk;
    pk.x = f2bf_u(av[0]) | (f2bf_u(av[1]) << 16);
    pk.y = f2bf_u(av[2]) | (f2bf_u(av[3]) << 16);
    *(uint2*)(vp + off) = pk;
  }
}

// ---------------- stage one 32-key tile (12KB) into LDS ----------------
// 12 chunks of 1KB (512 shorts): 0-3 Khi, 4-7 Klo, 8-11 V. 8 waves: w<4 -> 2.
static __device__ __forceinline__ void stage_tile32(
    const unsigned short* __restrict__ kph, const unsigned short* __restrict__ kpl,
    const unsigned short* __restrict__ vp, int kti,
    unsigned short* lds, int w, int l) {
  const unsigned short* kb = kph + kti * 2048;
  const unsigned short* lb = kpl + kti * 2048;
  const unsigned short* vb = vp + kti * 2048;
  {
    int chunk = w;  // waves 0..7 -> chunks 0..7
    const unsigned short* src = (chunk < 4) ? kb : lb;
    GLOAD_LDS16(src + (chunk & 3) * 512 + l * 8, lds + chunk * 512);
  }
  if (w < 4) {      // waves 0..3 -> chunks 8..11 (V)
    int chunk = 8 + w;
    GLOAD_LDS16(vb + (chunk & 3) * 512 + l * 8, lds + chunk * 512);
  }
}

// ---------------- flash attention ----------------
// grid 512 = 64 qblocks x 8 key-splits; 512 thr (8 waves); wave: 16 q x 1024 keys.
__global__ __launch_bounds__(512, 4) void attn8(
    const unsigned short* __restrict__ qhp, const unsigned short* __restrict__ qlp,
    const unsigned short* __restrict__ kph, const unsigned short* __restrict__ kpl,
    const unsigned short* __restrict__ vp,
    unsigned short* __restrict__ pnb, float* __restrict__ pden, float* __restrict__ pM) {
  __shared__ unsigned short kv_lds[2 * 6144];   // 2 x 12KB tile buffers
  __shared__ unsigned short P_lds[8 * 16 * 40]; // per-wave P transpose (32 cols + 8 pad)

  const int tid = threadIdx.x, w = tid >> 6, l = tid & 63;
  const int l15 = l & 15, g = l >> 4;
  const int qblk = blockIdx.x >> 3, ks = blockIdx.x & 7;
  const int wq0 = qblk * 128 + w * 16;

  // Q fragments (B-operand of swapped QK^T), 16 q rows
  bf16x8 qhf[2], qlf[2];
#pragma unroll
  for (int c = 0; c < 2; c++) {
    int row = wq0 + l15;
    qhf[c] = *(const bf16x8*)(qhp + row * DK + c * 32 + g * 8);
    qlf[c] = *(const bf16x8*)(qlp + row * DK + c * 32 + g * 8);
  }

  const short onec = (short)0x3F80;
  const bf16x8 ones = {onec, onec, onec, onec, onec, onec, onec, onec};

  f32x4 accO[4], accL = {0.f, 0.f, 0.f, 0.f};
  float m = -1e30f;
#pragma unroll
  for (int ds = 0; ds < 4; ds++) accO[ds] = f32x4{0.f, 0.f, 0.f, 0.f};

  const int kti0 = ks * 32;  // 32-key groups; tile t -> group kti0 + t
  stage_tile32(kph, kpl, vp, kti0, kv_lds, w, l);
  __syncthreads();

  for (int t = 0; t < 32; ++t) {
    const int cb = (t & 1) ? 6144 : 0;
    const int pb = 6144 - cb;
    const int ktin = kti0 + ((t < 31) ? (t + 1) : t);
    stage_tile32(kph, kpl, vp, ktin, kv_lds + pb, w, l);

    const unsigned short* Kh = kv_lds + cb;
    const unsigned short* Kl = Kh + 2048;
    const unsigned short* Vv = Kh + 4096;

    // S^T = K Q^T for 32 keys (2 subtiles): col = q = lane&15, row = key
    f32x4 st[2];
#pragma unroll
    for (int s = 0; s < 2; s++) {
      bf16x8 khf[2], klf[2];
#pragma unroll
      for (int c = 0; c < 2; c++) {
        const int off = s * 1024 + c * 512 + l * 8;
        khf[c] = *(const bf16x8*)(Kh + off);
        klf[c] = *(const bf16x8*)(Kl + off);
      }
      __builtin_amdgcn_s_setprio(1);
      f32x4 sa = {0.f, 0.f, 0.f, 0.f};
      sa = __builtin_amdgcn_mfma_f32_16x16x32_bf16(khf[0], qhf[0], sa, 0, 0, 0);
      sa = __builtin_amdgcn_mfma_f32_16x16x32_bf16(khf[1], qhf[1], sa, 0, 0, 0);
      sa = __builtin_amdgcn_mfma_f32_16x16x32_bf16(khf[0], qlf[0], sa, 0, 0, 0);
      sa = __builtin_amdgcn_mfma_f32_16x16x32_bf16(khf[1], qlf[1], sa, 0, 0, 0);
      sa = __builtin_amdgcn_mfma_f32_16x16x32_bf16(klf[0], qhf[0], sa, 0, 0, 0);
      sa = __builtin_amdgcn_mfma_f32_16x16x32_bf16(klf[1], qhf[1], sa, 0, 0, 0);
      st[s] = sa;
      __builtin_amdgcn_s_setprio(0);
    }

    // softmax (R3-proven: __expf, THR=8)
    float t0m = fmaxf(fmaxf(st[0][0], st[0][1]), fmaxf(st[0][2], st[0][3]));
    float t1m = fmaxf(fmaxf(st[1][0], st[1][1]), fmaxf(st[1][2], st[1][3]));
    float tm = fmaxf(t0m, t1m);
    tm = fmaxf(tm, __shfl_xor(tm, 16, 64));
    tm = fmaxf(tm, __shfl_xor(tm, 32, 64));
    if (__any(tm > m + 8.f)) {
      float mn = fmaxf(m, tm);
      float fac = __expf(m - mn);
      m = mn;
#pragma unroll
      for (int r = 0; r < 4; r++) {
        float fr = __shfl(fac, g * 4 + r, 64);
        accL[r] *= fr;
#pragma unroll
        for (int ds = 0; ds < 4; ds++) accO[ds][r] *= fr;
      }
    }
    // P = exp(S - m) -> per-wave LDS transpose (stride 40) -> b128 A-frag
    const int base = (w * 16 + l15) * 40;
#pragma unroll
    for (int s = 0; s < 2; s++) {
      float p0 = __expf(st[s][0] - m);
      float p1 = __expf(st[s][1] - m);
      float p2 = __expf(st[s][2] - m);
      float p3 = __expf(st[s][3] - m);
      *(unsigned*)&P_lds[base + s * 16 + g * 4]     = truncpk(p0, p1);
      *(unsigned*)&P_lds[base + s * 16 + g * 4 + 2] = truncpk(p2, p3);
    }
    bf16x8 pa = *(const bf16x8*)&P_lds[base + g * 8];

    __builtin_amdgcn_s_setprio(1);
    accL = __builtin_amdgcn_mfma_f32_16x16x32_bf16(pa, ones, accL, 0, 0, 0);
#pragma unroll
    for (int ds = 0; ds < 4; ds++) {
      bf16x8 vb = *(const bf16x8*)(Vv + ds * 512 + l * 8);
      accO[ds] = __builtin_amdgcn_mfma_f32_16x16x32_bf16(pa, vb, accO[ds], 0, 0, 0);
    }
    __builtin_amdgcn_s_setprio(0);

    __syncthreads();  // drains vmcnt (prefetch) + lgkm; swap buffers
  }

  // write per-(qblock, key-split) partials (num bf16, den/M fp32)
#pragma unroll
  for (int ds = 0; ds < 4; ds++)
#pragma unroll
    for (int r = 0; r < 4; r++)
      pnb[(size_t)ks * (N_TOK * DK) + (wq0 + g * 4 + r) * DK + ds * 16 + l15] =
          f2bf(accO[ds][r]);
  if (l15 == 0) {
#pragma unroll
    for (int r = 0; r < 4; r++) pden[ks * N_TOK + wq0 + g * 4 + r] = accL[r];
  }
  if (g == 0) pM[ks * N_TOK + wq0 + l15] = m;
}

// ---------------- merge 8 key-split partials ----------------
__global__ __launch_bounds__(256) void merge8(
    const unsigned short* __restrict__ pnb, const float* __restrict__ pden,
    const float* __restrict__ pM, float* __restrict__ out) {
  int i = blockIdx.x * 256 + threadIdx.x;
  int q = i >> 6, d = i & 63;
  float M = -1e30f;
#pragma unroll
  for (int s = 0; s < 8; s++) M = fmaxf(M, pM[s * N_TOK + q]);
  float num = 0.f, den = 0.f;
#pragma unroll
  for (int s = 0; s < 8; s++) {
    float e = __expf(pM[s * N_TOK + q] - M);
    num += bf2f(pnb[(size_t)s * (N_TOK * DK) + q * DK + d]) * e;
    den += pden[s * N_TOK + q] * e;
  }
  out[i] = num / den;
}

// ---------------- host launch ----------------
extern "C" void kernel_launch(void* const* d_in, const int* in_sizes, int n_in,
                              void* d_out, int out_size, void* d_ws, size_t ws_size,
                              hipStream_t stream) {
  (void)in_sizes; (void)n_in; (void)out_size; (void)ws_size;
  const float* X  = (const float*)d_in[0];
  const float* Wq = (const float*)d_in[1];
  const float* Wk = (const float*)d_in[2];
  const float* Wv = (const float*)d_in[3];

  char* base = (char*)d_ws;
  unsigned short* pnb = (unsigned short*)(base);                  // 8 MB [8][8192][64] bf16
  unsigned short* qhp = (unsigned short*)(base + 16777216);       // 1 MB
  unsigned short* qlp = (unsigned short*)(base + 17825792);       // 1 MB
  unsigned short* kph = (unsigned short*)(base + 18874368);       // 1 MB
  unsigned short* kpl = (unsigned short*)(base + 19922944);       // 1 MB
  unsigned short* vp  = (unsigned short*)(base + 20971520);       // 1 MB
  float* pden = (float*)(base + 22020096);                        // 256 KB
  float* pM   = (float*)(base + 22544384);                        // 256 KB

  qkv3<<<N_TOK / 16, 256, 0, stream>>>(X, Wq, Wk, Wv, qhp, qlp, kph, kpl, vp);
  attn8<<<512, 512, 0, stream>>>(qhp, qlp, kph, kpl, vp, pnb, pden, pM);
  merge8<<<(N_TOK * DK) / 256, 256, 0, stream>>>(pnb, pden, pM, (float*)d_out);
}